// Round 1
// baseline (290386.279 us; speedup 1.0000x reference)
//
#include <hip/hip_runtime.h>
#include <stdint.h>

typedef unsigned short ushort_t;
typedef __attribute__((ext_vector_type(8))) short short8;
typedef __attribute__((ext_vector_type(4))) float f32x4;

#define WS_W0T_HI 0u
#define WS_W0T_LO (2u<<20)
#define WS_WST_HI (4u<<20)
#define WS_WST_LO (12u<<20)
#define WS_ST     (20u<<20)
#define WS_BAR    (26u<<20)

#define SLOT_ELEMS 262144   // per state slot (hi+lo planes), elements
#define PLANE 131072        // 256*512

__device__ __forceinline__ ushort_t f2bf(float f) {
  unsigned u = __float_as_uint(f);
  u += 0x7FFFu + ((u >> 16) & 1u);          // RNE to bf16
  return (ushort_t)(u >> 16);
}
__device__ __forceinline__ float bf2f(ushort_t h) {
  return __uint_as_float(((unsigned)h) << 16);
}
__device__ __forceinline__ float sigf(float v) { return 1.f / (1.f + __expf(-v)); }
__device__ __forceinline__ float actf(int a, float h) {
  if (a == 0) return tanhf(h);
  if (a == 1) return fmaxf(h, 0.f);
  if (a == 2) return h;
  return sigf(h);
}

// ---------------- prep: transpose + hi/lo split weights; convert h0, x[0] ----
extern "C" __global__ void prep_kernel(const float* __restrict__ W0,
                                       const float* __restrict__ Ws,
                                       const float* __restrict__ x,
                                       const float* __restrict__ h0,
                                       char* __restrict__ ws) {
  ushort_t* w0h = (ushort_t*)(ws + WS_W0T_HI);
  ushort_t* w0l = (ushort_t*)(ws + WS_W0T_LO);
  ushort_t* wsh = (ushort_t*)(ws + WS_WST_HI);
  ushort_t* wsl = (ushort_t*)(ws + WS_WST_LO);
  ushort_t* st  = (ushort_t*)(ws + WS_ST);
  const long N0 = 1048576, N1 = 4194304, N2 = 131072;
  long total = N0 + N1 + N2 + N2;
  for (long idx = (long)blockIdx.x * blockDim.x + threadIdx.x; idx < total;
       idx += (long)gridDim.x * blockDim.x) {
    if (idx < N0) {                       // W0T[j][k] from W0[k][j], K=1024
      int k = (int)(idx >> 10), j = (int)(idx & 1023);
      float v = W0[k * 1024 + j];
      ushort_t hi = f2bf(v);
      w0h[j * 1024 + k] = hi;
      w0l[j * 1024 + k] = f2bf(v - bf2f(hi));
    } else if (idx < N0 + N1) {           // WsT[i][j][k] from Ws[i][k][j], K=512
      long r = idx - N0;
      int i = (int)(r >> 19);
      int r2 = (int)(r & 524287);
      int k = r2 >> 10, j = r2 & 1023;
      float v = Ws[(long)i * 524288 + k * 1024 + j];
      ushort_t hi = f2bf(v);
      wsh[(long)i * 524288 + j * 512 + k] = hi;
      wsl[(long)i * 524288 + j * 512 + k] = f2bf(v - bf2f(hi));
    } else if (idx < N0 + N1 + N2) {      // h0 -> slot 9
      int e = (int)(idx - N0 - N1);
      float v = h0[e];
      ushort_t hi = f2bf(v);
      st[9 * SLOT_ELEMS + e] = hi;
      st[9 * SLOT_ELEMS + PLANE + e] = f2bf(v - bf2f(hi));
    } else {                              // x[0] -> slot 10
      int e = (int)(idx - N0 - N1 - N2);
      float v = x[e];
      ushort_t hi = f2bf(v);
      st[10 * SLOT_ELEMS + e] = hi;
      st[10 * SLOT_ELEMS + PLANE + e] = f2bf(v - bf2f(hi));
    }
  }
}

// ---------------- grid barrier: 512 WGs, two-level tree --------------------
__device__ __forceinline__ void gbar(unsigned* bar, int wg) {
  __syncthreads();
  if (threadIdx.x == 0) {
    __threadfence();  // agent-scope release of this WG's global writes
    unsigned g = __hip_atomic_load(bar, __ATOMIC_ACQUIRE, __HIP_MEMORY_SCOPE_AGENT);
    unsigned grp = (unsigned)wg >> 4;     // 32 groups of 16 WGs
    unsigned a = __hip_atomic_fetch_add(bar + 64 + grp * 32, 1u,
                                        __ATOMIC_ACQ_REL, __HIP_MEMORY_SCOPE_AGENT);
    if (a == 15u) {
      __hip_atomic_store(bar + 64 + grp * 32, 0u, __ATOMIC_RELAXED, __HIP_MEMORY_SCOPE_AGENT);
      unsigned r = __hip_atomic_fetch_add(bar + 32, 1u,
                                          __ATOMIC_ACQ_REL, __HIP_MEMORY_SCOPE_AGENT);
      if (r == 31u) {
        __hip_atomic_store(bar + 32, 0u, __ATOMIC_RELAXED, __HIP_MEMORY_SCOPE_AGENT);
        __hip_atomic_store(bar, g + 1u, __ATOMIC_RELEASE, __HIP_MEMORY_SCOPE_AGENT);
      }
    }
    while (__hip_atomic_load(bar, __ATOMIC_ACQUIRE, __HIP_MEMORY_SCOPE_AGENT) == g) {
      __builtin_amdgcn_s_sleep(1);
    }
  }
  __syncthreads();
}

struct Tgt { int src; int dst; int act; const ushort_t* wh; const ushort_t* wl; };

// ---------------- one stage: bf16x3 MFMA matmul(s) into LDS tiles ----------
__device__ void run_stage(const Tgt* tg, int nt, int K, int isA,
                          ushort_t* st,
                          float (*sC)[32][16], float (*sH)[32][16],
                          int busy, int r0, int j0) {
  if (!busy) return;
  int tid = threadIdx.x;
  int wave = tid >> 6, lane = tid & 63;
  int li = lane & 15, lb = lane >> 4;
  int rh = wave & 1, ch = wave >> 1;      // 4 waves: row-half x col-half(c/h)
  int arow = r0 + 16 * rh + li;
  for (int g = 0; g < nt; ++g) {
    f32x4 acc = {0.f, 0.f, 0.f, 0.f};
    const ushort_t* ah = st + tg[g].src * SLOT_ELEMS;
    int jc = j0 + li + (ch ? 512 : 0);
    const ushort_t* wh = tg[g].wh + jc * K;
    const ushort_t* wl = tg[g].wl + jc * K;
    for (int kk = 0; kk < K; kk += 32) {
      int ka = kk + 8 * lb;
      const ushort_t* ap;
      int k2;
      if (isA) {                          // xh = [x(slot10) | h(slot9)]
        ap = st + ((ka < 512) ? 10 : 9) * SLOT_ELEMS;
        k2 = ka & 511;
      } else { ap = ah; k2 = ka; }
      short8 a_h = *(const short8*)(ap + arow * 512 + k2);
      short8 a_l = *(const short8*)(ap + PLANE + arow * 512 + k2);
      short8 b_h = *(const short8*)(wh + ka);
      short8 b_l = *(const short8*)(wl + ka);
      acc = __builtin_amdgcn_mfma_f32_16x16x32_bf16(a_h, b_h, acc, 0, 0, 0);
      acc = __builtin_amdgcn_mfma_f32_16x16x32_bf16(a_h, b_l, acc, 0, 0, 0);
      acc = __builtin_amdgcn_mfma_f32_16x16x32_bf16(a_l, b_h, acc, 0, 0, 0);
    }
#pragma unroll
    for (int v = 0; v < 4; ++v) {         // C/D: col=lane&15, row=(lane>>4)*4+v
      int rl = 16 * rh + 4 * lb + v;
      if (ch) sH[g][rl][li] = acc[v];
      else    sC[g][rl][li] = acc[v];
    }
  }
  __syncthreads();
}

// ---------------- generic highway-gate epilogue ----------------------------
__device__ void epi_generic(const Tgt* tg, int nt, ushort_t* st,
                            float (*sC)[32][16], float (*sH)[32][16],
                            int busy, int r0, int j0) {
  if (!busy) return;
  for (int e = threadIdx.x; e < 512; e += 256) {
    int rl = e >> 4, cl = e & 15;
    int o = (r0 + rl) * 512 + (j0 + cl);
    for (int g = 0; g < nt; ++g) {
      float c = sC[g][rl][cl], h = sH[g][rl][cl];
      const ushort_t* spp = st + tg[g].src * SLOT_ELEMS;
      float sp = bf2f(spp[o]) + bf2f(spp[PLANE + o]);
      float s = sp + sigf(c) * (actf(tg[g].act, h) - sp);
      ushort_t hi = f2bf(s);
      ushort_t* d = st + tg[g].dst * SLOT_ELEMS;
      d[o] = hi;
      d[PLANE + o] = f2bf(s - bf2f(hi));
    }
  }
}

// ---------------- stage E epilogue: s6,s8 + mean + h write -----------------
__device__ void epi_E(ushort_t* st, float* out, int t,
                      float (*sC)[32][16], float (*sH)[32][16],
                      int busy, int r0, int j0) {
  if (!busy) return;
  for (int e = threadIdx.x; e < 512; e += 256) {
    int rl = e >> 4, cl = e & 15;
    int o = (r0 + rl) * 512 + (j0 + cl);
    float sp5 = bf2f(st[5 * SLOT_ELEMS + o]) + bf2f(st[5 * SLOT_ELEMS + PLANE + o]);
    float s6 = sp5 + sigf(sC[0][rl][cl]) * (sigf(sH[0][rl][cl]) - sp5);
    float s8 = sp5 + sigf(sC[1][rl][cl]) * (fmaxf(sH[1][rl][cl], 0.f) - sp5);
    float sum = s6 + s8 + sp5;
    const int slots[5] = {1, 2, 3, 4, 7};
#pragma unroll
    for (int q = 0; q < 5; ++q) {
      int s = slots[q];
      sum += bf2f(st[s * SLOT_ELEMS + o]) + bf2f(st[s * SLOT_ELEMS + PLANE + o]);
    }
    float hn = sum * 0.125f;
    out[(size_t)t * 131072 + o] = hn;
    if (t == 399) out[(size_t)400 * 131072 + o] = hn;
    ushort_t hi = f2bf(hn);
    st[9 * SLOT_ELEMS + o] = hi;
    st[9 * SLOT_ELEMS + PLANE + o] = f2bf(hn - bf2f(hi));
  }
}

// ---------------- main persistent cooperative kernel -----------------------
extern "C" __global__ void __launch_bounds__(256, 2)
rnn_main(const float* __restrict__ x, float* __restrict__ out, char* __restrict__ ws) {
  __shared__ float sC[3][32][16];
  __shared__ float sH[3][32][16];
  ushort_t* st = (ushort_t*)(ws + WS_ST);
  unsigned* bar = (unsigned*)(ws + WS_BAR);
  const ushort_t* w0h = (const ushort_t*)(ws + WS_W0T_HI);
  const ushort_t* w0l = (const ushort_t*)(ws + WS_W0T_LO);
  const ushort_t* wsh = (const ushort_t*)(ws + WS_WST_HI);
  const ushort_t* wsl = (const ushort_t*)(ws + WS_WST_LO);

  int wg = blockIdx.x;
  int xcd = wg & 7, sl = wg >> 3;
  int busy = (sl < 32);                 // 256 busy WGs cover the 8x32 job grid
  int rt = sl >> 2, pt = 4 * xcd + (sl & 3);   // pairtile pinned to XCD for L2 reuse
  int r0 = rt * 32, j0 = pt * 16;

  Tgt tA[1] = {{9, 0, 0, w0h, w0l}};                                  // s0: tanh, sp=h_prev
  Tgt tB[1] = {{0, 1, 0, wsh + 0 * 524288, wsl + 0 * 524288}};        // s1 = f(s0), tanh
  Tgt tC[3] = {{1, 2, 1, wsh + 1 * 524288, wsl + 1 * 524288},         // s2 relu
               {1, 3, 1, wsh + 2 * 524288, wsl + 2 * 524288},         // s3 relu
               {1, 4, 2, wsh + 3 * 524288, wsl + 3 * 524288}};        // s4 identity
  Tgt tD[2] = {{2, 5, 0, wsh + 4 * 524288, wsl + 4 * 524288},         // s5 = f(s2) tanh
               {3, 7, 0, wsh + 6 * 524288, wsl + 6 * 524288}};        // s7 = f(s3) tanh
  Tgt tE[2] = {{5, 6, 3, wsh + 5 * 524288, wsl + 5 * 524288},         // s6 = f(s5) sigmoid
               {5, 8, 1, wsh + 7 * 524288, wsl + 7 * 524288}};        // s8 = f(s5) relu

  for (int t = 0; t < 400; ++t) {
    run_stage(tA, 1, 1024, 1, st, sC, sH, busy, r0, j0);
    epi_generic(tA, 1, st, sC, sH, busy, r0, j0);
    gbar(bar, wg);
    run_stage(tB, 1, 512, 0, st, sC, sH, busy, r0, j0);
    epi_generic(tB, 1, st, sC, sH, busy, r0, j0);
    gbar(bar, wg);
    run_stage(tC, 3, 512, 0, st, sC, sH, busy, r0, j0);
    epi_generic(tC, 3, st, sC, sH, busy, r0, j0);
    gbar(bar, wg);
    run_stage(tD, 2, 512, 0, st, sC, sH, busy, r0, j0);
    epi_generic(tD, 2, st, sC, sH, busy, r0, j0);
    gbar(bar, wg);
    run_stage(tE, 2, 512, 0, st, sC, sH, busy, r0, j0);
    epi_E(st, out, t, sC, sH, busy, r0, j0);
    if (t + 1 < 400) {                  // pre-convert x[t+1] -> slot 10 (all 512 WGs)
      int g2 = wg * 256 + threadIdx.x;  // exactly covers 131072 elements
      float v = x[(size_t)(t + 1) * 131072 + g2];
      ushort_t hi = f2bf(v);
      st[10 * SLOT_ELEMS + g2] = hi;
      st[10 * SLOT_ELEMS + PLANE + g2] = f2bf(v - bf2f(hi));
    }
    gbar(bar, wg);
  }
}

// ---------------- host launch ----------------------------------------------
extern "C" void kernel_launch(void* const* d_in, const int* in_sizes, int n_in,
                              void* d_out, int out_size, void* d_ws, size_t ws_size,
                              hipStream_t stream) {
  const float* x  = (const float*)d_in[0];
  const float* h0 = (const float*)d_in[1];
  const float* W0 = (const float*)d_in[2];
  const float* Ws = (const float*)d_in[3];
  float* out = (float*)d_out;
  char* ws = (char*)d_ws;

  (void)in_sizes; (void)n_in; (void)out_size; (void)ws_size;

  // zero the barrier flags (ws is poisoned 0xAA once; must re-zero every call)
  (void)hipMemsetAsync(ws + WS_BAR, 0, 8192, stream);

  hipLaunchKernelGGL(prep_kernel, dim3(2048), dim3(256), 0, stream, W0, Ws, x, h0, ws);

  void* args[3] = {(void*)&x, (void*)&out, (void*)&ws};
  (void)hipLaunchCooperativeKernel((void*)rnn_main, dim3(512), dim3(256), args, 0, stream);
}

// Round 2
// 52682.312 us; speedup vs baseline: 5.5120x; 5.5120x over previous
//
#include <hip/hip_runtime.h>
#include <stdint.h>

typedef unsigned short ushort_t;
typedef __attribute__((ext_vector_type(8))) short short8;
typedef __attribute__((ext_vector_type(16))) float f32x16;

#define WS_W0T_HI 0u
#define WS_W0T_LO (2u<<20)
#define WS_WST_HI (4u<<20)
#define WS_WST_LO (12u<<20)
#define WS_ST     (20u<<20)
#define WS_BAR    (26u<<20)

#define SLOT_ELEMS 262144   // per state slot (hi plane + lo plane), elements
#define PLANE 131072        // 256*512

// global state slots: 0=h, 1=s0, 2=s1, 3=s2, 4=s3, 5=s5, 6=x(even t), 7=x(odd t)

__device__ __forceinline__ ushort_t f2bf(float f) {
  unsigned u = __float_as_uint(f);
  u += 0x7FFFu + ((u >> 16) & 1u);          // RNE to bf16
  return (ushort_t)(u >> 16);
}
__device__ __forceinline__ float bf2f(ushort_t h) {
  return __uint_as_float(((unsigned)h) << 16);
}
__device__ __forceinline__ float sigf(float v) { return 1.f / (1.f + __expf(-v)); }

// ---------------- prep: transpose + hi/lo split weights; convert h0, x[0] ----
extern "C" __global__ void prep_kernel(const float* __restrict__ W0,
                                       const float* __restrict__ Ws,
                                       const float* __restrict__ x,
                                       const float* __restrict__ h0,
                                       char* __restrict__ ws) {
  ushort_t* w0h = (ushort_t*)(ws + WS_W0T_HI);
  ushort_t* w0l = (ushort_t*)(ws + WS_W0T_LO);
  ushort_t* wsh = (ushort_t*)(ws + WS_WST_HI);
  ushort_t* wsl = (ushort_t*)(ws + WS_WST_LO);
  ushort_t* st  = (ushort_t*)(ws + WS_ST);
  const long N0 = 1048576, N1 = 4194304, N2 = 131072;
  long total = N0 + N1 + N2 + N2;
  for (long idx = (long)blockIdx.x * blockDim.x + threadIdx.x; idx < total;
       idx += (long)gridDim.x * blockDim.x) {
    if (idx < N0) {                       // W0T[j][k] from W0[k][j], K=1024
      int k = (int)(idx >> 10), j = (int)(idx & 1023);
      float v = W0[k * 1024 + j];
      ushort_t hi = f2bf(v);
      w0h[j * 1024 + k] = hi;
      w0l[j * 1024 + k] = f2bf(v - bf2f(hi));
    } else if (idx < N0 + N1) {           // WsT[i][j][k] from Ws[i][k][j], K=512
      long r = idx - N0;
      int i = (int)(r >> 19);
      int r2 = (int)(r & 524287);
      int k = r2 >> 10, j = r2 & 1023;
      float v = Ws[(long)i * 524288 + k * 1024 + j];
      ushort_t hi = f2bf(v);
      wsh[(long)i * 524288 + j * 512 + k] = hi;
      wsl[(long)i * 524288 + j * 512 + k] = f2bf(v - bf2f(hi));
    } else if (idx < N0 + N1 + N2) {      // h0 -> slot 0
      int e = (int)(idx - N0 - N1);
      float v = h0[e];
      ushort_t hi = f2bf(v);
      st[0 * SLOT_ELEMS + e] = hi;
      st[0 * SLOT_ELEMS + PLANE + e] = f2bf(v - bf2f(hi));
    } else {                              // x[0] -> slot 6 (t=0 is even)
      int e = (int)(idx - N0 - N1 - N2);
      float v = x[e];
      ushort_t hi = f2bf(v);
      st[6 * SLOT_ELEMS + e] = hi;
      st[6 * SLOT_ELEMS + PLANE + e] = f2bf(v - bf2f(hi));
    }
  }
}

// ---------------- per-group barrier (32 WGs), monotonic generation ---------
__device__ __forceinline__ void gbar(unsigned* bar, int g, unsigned gen) {
  __syncthreads();   // also drains vmcnt/lgkm for every wave of the WG
  if (threadIdx.x == 0) {
    __threadfence();  // agent-scope release of this WG's global writes
    unsigned* cnt = bar + g * 32;
    unsigned* flg = bar + g * 32 + 16;
    unsigned a = __hip_atomic_fetch_add(cnt, 1u, __ATOMIC_ACQ_REL, __HIP_MEMORY_SCOPE_AGENT);
    if (a == 31u) {
      __hip_atomic_store(cnt, 0u, __ATOMIC_RELAXED, __HIP_MEMORY_SCOPE_AGENT);
      __hip_atomic_store(flg, gen, __ATOMIC_RELEASE, __HIP_MEMORY_SCOPE_AGENT);
    } else {
      while ((int)(__hip_atomic_load(flg, __ATOMIC_ACQUIRE, __HIP_MEMORY_SCOPE_AGENT) - gen) < 0)
        __builtin_amdgcn_s_sleep(2);
    }
  }
  __syncthreads();
}

__device__ __forceinline__ f32x16 mfma3(short8 ah, short8 al, short8 bh, short8 bl, f32x16 acc) {
  acc = __builtin_amdgcn_mfma_f32_32x32x16_bf16(ah, bh, acc, 0, 0, 0);
  acc = __builtin_amdgcn_mfma_f32_32x32x16_bf16(ah, bl, acc, 0, 0, 0);
  acc = __builtin_amdgcn_mfma_f32_32x32x16_bf16(al, bh, acc, 0, 0, 0);
  return acc;
}

// shared-A matmul: NP B-matrices against one A (with optional x|h concat split)
template<int NP, int NBLK, bool XH>
__device__ __forceinline__ void mm_sharedA(const ushort_t* a1, const ushort_t* a2,
                                           const ushort_t* const (&bh)[NP],
                                           const ushort_t* const (&bl)[NP],
                                           int aoff, int boff, int kw,
                                           f32x16 (&acc)[NP]) {
#pragma unroll
  for (int j = 0; j < NBLK; ++j) {
    int kq = j * 128 + kw;
    const ushort_t* ap = (XH && j >= 4) ? a2 : a1;
    int kk = (XH && j >= 4) ? (kq - 512) : kq;
    short8 a_h = *(const short8*)(ap + aoff + kk);
    short8 a_l = *(const short8*)(ap + PLANE + aoff + kk);
#pragma unroll
    for (int p = 0; p < NP; ++p) {
      short8 b_h = *(const short8*)(bh[p] + boff + kq);
      short8 b_l = *(const short8*)(bl[p] + boff + kq);
      acc[p] = mfma3(a_h, a_l, b_h, b_l, acc[p]);
    }
  }
}

// independent-A matmul: pair p uses A[p] and B[p] (stage D)
template<int NP, int NBLK>
__device__ __forceinline__ void mm_pairA(const ushort_t* const (&as)[NP],
                                         const ushort_t* const (&bh)[NP],
                                         const ushort_t* const (&bl)[NP],
                                         int aoff, int boff, int kw,
                                         f32x16 (&acc)[NP]) {
#pragma unroll
  for (int j = 0; j < NBLK; ++j) {
    int kq = j * 128 + kw;
#pragma unroll
    for (int p = 0; p < NP; ++p) {
      short8 a_h = *(const short8*)(as[p] + aoff + kq);
      short8 a_l = *(const short8*)(as[p] + PLANE + aoff + kq);
      short8 b_h = *(const short8*)(bh[p] + boff + kq);
      short8 b_l = *(const short8*)(bl[p] + boff + kq);
      acc[p] = mfma3(a_h, a_l, b_h, b_l, acc[p]);
    }
  }
}

template<int NP>
__device__ __forceinline__ void store_partials(float* pp, const f32x16 (&acc)[NP],
                                               int w, int lane) {
  int col = lane & 31, hi = lane >> 5;
#pragma unroll
  for (int p = 0; p < NP; ++p) {
#pragma unroll
    for (int r = 0; r < 16; ++r) {
      int row = (r & 3) + 8 * (r >> 2) + 4 * hi;   // verified 32x32 C/D layout
      pp[(w * NP + p) * 1056 + row * 33 + col] = acc[p][r];
    }
  }
}

template<int NP>
__device__ __forceinline__ void red2(const float* pp, int p, int row, int cp,
                                     float& c, float& h) {
  float cs = 0.f, hs = 0.f;
#pragma unroll
  for (int w = 0; w < 8; ++w) {
    cs += pp[(w * NP + p) * 1056 + row * 33 + cp];
    hs += pp[(w * NP + p) * 1056 + row * 33 + cp + 16];
  }
  c = cs; h = hs;
}

// ---------------- main persistent cooperative kernel -----------------------
extern "C" __global__ void __launch_bounds__(512, 1)
rnn_main(const float* __restrict__ x, float* __restrict__ out, char* __restrict__ ws) {
  __shared__ float pp[8 * 3 * 1056];      // 8-wave partials, up to 3 targets
  __shared__ float lst[6][32][16];        // WG-local f32 state tiles: h,s0,s1,s2,s3,s5
  ushort_t* stg = (ushort_t*)(ws + WS_ST);
  unsigned* bar = (unsigned*)(ws + WS_BAR);
  const ushort_t* w0h = (const ushort_t*)(ws + WS_W0T_HI);
  const ushort_t* w0l = (const ushort_t*)(ws + WS_W0T_LO);
  const ushort_t* wsh = (const ushort_t*)(ws + WS_WST_HI);
  const ushort_t* wsl = (const ushort_t*)(ws + WS_WST_LO);

  const int tid = threadIdx.x;
  const int wg = blockIdx.x;
  const int rt = wg >> 5, pt = wg & 31;   // 8 row-groups x 32 col-WGs; xcd = wg%8 tracks pt%8
  const int g = rt;
  const int r0 = rt * 32;
  const int w = tid >> 6, lane = tid & 63;
  const int kw = w * 16 + (lane >> 5) * 8;            // this wave's K-offset within 128-block
  const int aoff = (r0 + (lane & 31)) * 512;          // A-frag row offset (elements)
  const int vcl = lane & 31;
  const int jc = pt * 16 + (vcl & 15) + (vcl >> 4) * 512;  // virtual col -> weight col j
  const int b512 = jc * 512, b1024 = jc * 1024;

  const int erow = tid >> 4, ecp = tid & 15;          // epilogue coords (512 pairs)
  const int eo = (r0 + erow) * 512 + pt * 16 + ecp;   // global state element

  // init local h tile from global slot 0 (written by prep)
  lst[0][erow][ecp] = bf2f(stg[eo]) + bf2f(stg[PLANE + eo]);
  __syncthreads();

  unsigned gen = 1;
  float sumreg = 0.f;

  for (int t = 0; t < 400; ++t) {
    const ushort_t* xs = stg + (size_t)(6 + (t & 1)) * SLOT_ELEMS;

    // ---- stage A: s0 = h + sig(c)*(tanh(h0c) - h), A = [x | h], W0 (K=1024)
    {
      f32x16 acc[1] = {};
      const ushort_t* bh[1] = {w0h};
      const ushort_t* bl[1] = {w0l};
      mm_sharedA<1, 8, true>(xs, stg + 0 * SLOT_ELEMS, bh, bl, aoff, b1024, kw, acc);
      __syncthreads();
      store_partials<1>(pp, acc, w, lane);
      __syncthreads();
      float c, h; red2<1>(pp, 0, erow, ecp, c, h);
      float sp = lst[0][erow][ecp];
      float s = sp + sigf(c) * (tanhf(h) - sp);
      lst[1][erow][ecp] = s;
      ushort_t hb = f2bf(s);
      stg[1 * SLOT_ELEMS + eo] = hb;
      stg[1 * SLOT_ELEMS + PLANE + eo] = f2bf(s - bf2f(hb));
    }
    gbar(bar, g, gen++);

    // ---- stage B: s1 = s0 + sig(c)*(tanh(h) - s0), Ws[0]
    {
      f32x16 acc[1] = {};
      const ushort_t* bh[1] = {wsh + 0 * 524288};
      const ushort_t* bl[1] = {wsl + 0 * 524288};
      mm_sharedA<1, 4, false>(stg + 1 * SLOT_ELEMS, stg, bh, bl, aoff, b512, kw, acc);
      __syncthreads();
      store_partials<1>(pp, acc, w, lane);
      __syncthreads();
      float c, h; red2<1>(pp, 0, erow, ecp, c, h);
      float sp = lst[1][erow][ecp];
      float s = sp + sigf(c) * (tanhf(h) - sp);
      lst[2][erow][ecp] = s;
      sumreg += s;
      ushort_t hb = f2bf(s);
      stg[2 * SLOT_ELEMS + eo] = hb;
      stg[2 * SLOT_ELEMS + PLANE + eo] = f2bf(s - bf2f(hb));
    }
    gbar(bar, g, gen++);

    // ---- stage C: s2(relu,Ws[1]) s3(relu,Ws[2]) s4(ident,Ws[3]), all from s1
    {
      f32x16 acc[3] = {};
      const ushort_t* bh[3] = {wsh + 1 * 524288, wsh + 2 * 524288, wsh + 3 * 524288};
      const ushort_t* bl[3] = {wsl + 1 * 524288, wsl + 2 * 524288, wsl + 3 * 524288};
      mm_sharedA<3, 4, false>(stg + 2 * SLOT_ELEMS, stg, bh, bl, aoff, b512, kw, acc);
      __syncthreads();
      store_partials<3>(pp, acc, w, lane);
      __syncthreads();
      float sp = lst[2][erow][ecp];
      float c, h;
      red2<3>(pp, 0, erow, ecp, c, h);                 // s2: relu
      float s2v = sp + sigf(c) * (fmaxf(h, 0.f) - sp);
      lst[3][erow][ecp] = s2v; sumreg += s2v;
      ushort_t hb = f2bf(s2v);
      stg[3 * SLOT_ELEMS + eo] = hb;
      stg[3 * SLOT_ELEMS + PLANE + eo] = f2bf(s2v - bf2f(hb));
      red2<3>(pp, 1, erow, ecp, c, h);                 // s3: relu
      float s3v = sp + sigf(c) * (fmaxf(h, 0.f) - sp);
      lst[4][erow][ecp] = s3v; sumreg += s3v;
      hb = f2bf(s3v);
      stg[4 * SLOT_ELEMS + eo] = hb;
      stg[4 * SLOT_ELEMS + PLANE + eo] = f2bf(s3v - bf2f(hb));
      red2<3>(pp, 2, erow, ecp, c, h);                 // s4: identity, sum only
      sumreg += sp + sigf(c) * (h - sp);
    }
    gbar(bar, g, gen++);

    // ---- stage D: s5 = f(s2,tanh,Ws[4]); s7 = f(s3,tanh,Ws[6])
    {
      f32x16 acc[2] = {};
      const ushort_t* as[2] = {stg + 3 * SLOT_ELEMS, stg + 4 * SLOT_ELEMS};
      const ushort_t* bh[2] = {wsh + 4 * 524288, wsh + 6 * 524288};
      const ushort_t* bl[2] = {wsl + 4 * 524288, wsl + 6 * 524288};
      mm_pairA<2, 4>(as, bh, bl, aoff, b512, kw, acc);
      __syncthreads();
      store_partials<2>(pp, acc, w, lane);
      __syncthreads();
      float c, h;
      red2<2>(pp, 0, erow, ecp, c, h);                 // s5
      float sp = lst[3][erow][ecp];
      float s5v = sp + sigf(c) * (tanhf(h) - sp);
      lst[5][erow][ecp] = s5v; sumreg += s5v;
      ushort_t hb = f2bf(s5v);
      stg[5 * SLOT_ELEMS + eo] = hb;
      stg[5 * SLOT_ELEMS + PLANE + eo] = f2bf(s5v - bf2f(hb));
      red2<2>(pp, 1, erow, ecp, c, h);                 // s7: sum only
      float sp3 = lst[4][erow][ecp];
      sumreg += sp3 + sigf(c) * (tanhf(h) - sp3);
    }
    gbar(bar, g, gen++);

    // ---- stage E: s6 = f(s5,sigmoid,Ws[5]); s8 = f(s5,relu,Ws[7]); mean; h
    {
      f32x16 acc[2] = {};
      const ushort_t* bh[2] = {wsh + 5 * 524288, wsh + 7 * 524288};
      const ushort_t* bl[2] = {wsl + 5 * 524288, wsl + 7 * 524288};
      mm_sharedA<2, 4, false>(stg + 5 * SLOT_ELEMS, stg, bh, bl, aoff, b512, kw, acc);
      __syncthreads();
      store_partials<2>(pp, acc, w, lane);
      __syncthreads();
      float c, h;
      float sp = lst[5][erow][ecp];
      red2<2>(pp, 0, erow, ecp, c, h);                 // s6: sigmoid
      sumreg += sp + sigf(c) * (sigf(h) - sp);
      red2<2>(pp, 1, erow, ecp, c, h);                 // s8: relu
      sumreg += sp + sigf(c) * (fmaxf(h, 0.f) - sp);
      float hn = sumreg * 0.125f;
      out[(size_t)t * 131072 + eo] = hn;
      if (t == 399) out[(size_t)400 * 131072 + eo] = hn;
      lst[0][erow][ecp] = hn;
      ushort_t hb = f2bf(hn);
      stg[eo] = hb;
      stg[PLANE + eo] = f2bf(hn - bf2f(hb));
      sumreg = 0.f;
      if (t + 1 < 400) {                  // prefetch+convert x[t+1] into parity slot
        int gi = wg * 512 + tid;          // 256*512 = 131072, exact cover
        float v = x[(size_t)(t + 1) * 131072 + gi];
        ushort_t xb = f2bf(v);
        ushort_t* xd = stg + (size_t)(6 + ((t + 1) & 1)) * SLOT_ELEMS;
        xd[gi] = xb;
        xd[PLANE + gi] = f2bf(v - bf2f(xb));
      }
    }
    gbar(bar, g, gen++);
  }
}

// ---------------- host launch ----------------------------------------------
extern "C" void kernel_launch(void* const* d_in, const int* in_sizes, int n_in,
                              void* d_out, int out_size, void* d_ws, size_t ws_size,
                              hipStream_t stream) {
  const float* x  = (const float*)d_in[0];
  const float* h0 = (const float*)d_in[1];
  const float* W0 = (const float*)d_in[2];
  const float* Ws = (const float*)d_in[3];
  float* out = (float*)d_out;
  char* ws = (char*)d_ws;

  (void)in_sizes; (void)n_in; (void)out_size; (void)ws_size;

  (void)hipMemsetAsync(ws + WS_BAR, 0, 4096, stream);
  hipLaunchKernelGGL(prep_kernel, dim3(2048), dim3(256), 0, stream, W0, Ws, x, h0, ws);

  void* args[3] = {(void*)&x, (void*)&out, (void*)&ws};
  (void)hipLaunchCooperativeKernel((void*)rnn_main, dim3(256), dim3(512), args, 0, stream);
}

// Round 3
// 22453.725 us; speedup vs baseline: 12.9327x; 2.3463x over previous
//
#include <hip/hip_runtime.h>
#include <stdint.h>

typedef unsigned short ushort_t;
typedef unsigned long long u64;
typedef __attribute__((ext_vector_type(8))) short short8;
typedef __attribute__((ext_vector_type(4))) float f32x4;
typedef __attribute__((ext_vector_type(16))) float f32x16;

#define WS_W0T_HI 0u
#define WS_W0T_LO (2u<<20)
#define WS_WST_HI (4u<<20)
#define WS_WST_LO (12u<<20)
#define WS_ST     (20u<<20)
#define WS_BAR    (26u<<20)

#define SLOT_ELEMS 262144   // per state slot (hi plane + lo plane), elements
#define PLANE 131072        // 256*512

// state slots: 0=h, 1=s0, 2=s1, 3=s2, 4=s3, 5=s5

__device__ __forceinline__ ushort_t f2bf(float f) {
  unsigned u = __float_as_uint(f);
  u += 0x7FFFu + ((u >> 16) & 1u);          // RNE to bf16
  return (ushort_t)(u >> 16);
}
__device__ __forceinline__ float bf2f(ushort_t h) {
  return __uint_as_float(((unsigned)h) << 16);
}
__device__ __forceinline__ float sigf(float v) { return 1.f / (1.f + __expf(-v)); }

// 16B state-fragment load via 2x8B relaxed agent atomics: bypasses L1/L2
// (device-coherent via L3), NO cache invalidation side effects.
__device__ __forceinline__ short8 ald16(const ushort_t* p) {
  union { u64 q[2]; short8 s; } u;
  u.q[0] = __hip_atomic_load((const u64*)p,     __ATOMIC_RELAXED, __HIP_MEMORY_SCOPE_AGENT);
  u.q[1] = __hip_atomic_load((const u64*)p + 1, __ATOMIC_RELAXED, __HIP_MEMORY_SCOPE_AGENT);
  return u.s;
}

// convert 8 f32 (plain cached loads) -> bf16 hi/lo fragments
__device__ __forceinline__ void xcvt(const float* xp, short8& ah, short8& al) {
  f32x4 v0 = *(const f32x4*)xp;
  f32x4 v1 = *(const f32x4*)(xp + 4);
#pragma unroll
  for (int i = 0; i < 4; ++i) {
    ushort_t h0 = f2bf(v0[i]);
    ah[i] = (short)h0; al[i] = (short)f2bf(v0[i] - bf2f(h0));
    ushort_t h1 = f2bf(v1[i]);
    ah[i + 4] = (short)h1; al[i + 4] = (short)f2bf(v1[i] - bf2f(h1));
  }
}

// paired-column state store: even thread stores packed u32 (this col + tid^1's col)
// into hi and lo planes via relaxed agent atomics (device-visible, no fences).
__device__ __forceinline__ void st_state(ushort_t* slot, int eo, float s) {
  ushort_t hi = f2bf(s);
  ushort_t lo = f2bf(s - bf2f(hi));
  unsigned nh = __shfl_xor((unsigned)hi, 1, 64);
  unsigned nl = __shfl_xor((unsigned)lo, 1, 64);
  if ((threadIdx.x & 1) == 0) {
    unsigned wh = (unsigned)hi | (nh << 16);
    unsigned wl = (unsigned)lo | (nl << 16);
    __hip_atomic_store((unsigned*)(slot + eo), wh, __ATOMIC_RELAXED, __HIP_MEMORY_SCOPE_AGENT);
    __hip_atomic_store((unsigned*)(slot + PLANE + eo), wl, __ATOMIC_RELAXED, __HIP_MEMORY_SCOPE_AGENT);
  }
}

// ---------------- prep: transpose + hi/lo split weights; convert h0 ---------
extern "C" __global__ void prep_kernel(const float* __restrict__ W0,
                                       const float* __restrict__ Ws,
                                       const float* __restrict__ h0,
                                       char* __restrict__ ws) {
  ushort_t* w0h = (ushort_t*)(ws + WS_W0T_HI);
  ushort_t* w0l = (ushort_t*)(ws + WS_W0T_LO);
  ushort_t* wsh = (ushort_t*)(ws + WS_WST_HI);
  ushort_t* wsl = (ushort_t*)(ws + WS_WST_LO);
  ushort_t* st  = (ushort_t*)(ws + WS_ST);
  const long N0 = 1048576, N1 = 4194304, N2 = 131072;
  long total = N0 + N1 + N2;
  for (long idx = (long)blockIdx.x * blockDim.x + threadIdx.x; idx < total;
       idx += (long)gridDim.x * blockDim.x) {
    if (idx < N0) {                       // W0T[j][k] from W0[k][j], K=1024
      int k = (int)(idx >> 10), j = (int)(idx & 1023);
      float v = W0[k * 1024 + j];
      ushort_t hi = f2bf(v);
      w0h[j * 1024 + k] = hi;
      w0l[j * 1024 + k] = f2bf(v - bf2f(hi));
    } else if (idx < N0 + N1) {           // WsT[i][j][k] from Ws[i][k][j], K=512
      long r = idx - N0;
      int i = (int)(r >> 19);
      int r2 = (int)(r & 524287);
      int k = r2 >> 10, j = r2 & 1023;
      float v = Ws[(long)i * 524288 + k * 1024 + j];
      ushort_t hi = f2bf(v);
      wsh[(long)i * 524288 + j * 512 + k] = hi;
      wsl[(long)i * 524288 + j * 512 + k] = f2bf(v - bf2f(hi));
    } else {                              // h0 -> slot 0
      int e = (int)(idx - N0 - N1);
      float v = h0[e];
      ushort_t hi = f2bf(v);
      st[0 * SLOT_ELEMS + e] = hi;
      st[0 * SLOT_ELEMS + PLANE + e] = f2bf(v - bf2f(hi));
    }
  }
}

// -------- per-group barrier: per-WG epoch flags, relaxed atomics only -------
// arrival = one relaxed atomic store; wait = wave 0 polls the 32 group flags.
// Ordering: __syncthreads drains each wave's vmcnt (state stores acked at the
// coherence point) before the flag store. NO L2 writeback/invalidate anywhere.
__device__ __forceinline__ void gbar(unsigned* flags, int g, int pt, unsigned gen) {
  __syncthreads();
  if (threadIdx.x == 0)
    __hip_atomic_store(flags + (g * 32 + pt) * 16, gen, __ATOMIC_RELAXED, __HIP_MEMORY_SCOPE_AGENT);
  if (threadIdx.x < 64) {
    const unsigned* f = flags + (g * 32 + (threadIdx.x & 31)) * 16;
    while (__hip_atomic_load(f, __ATOMIC_RELAXED, __HIP_MEMORY_SCOPE_AGENT) < gen)
      __builtin_amdgcn_s_sleep(2);
  }
  __syncthreads();
  asm volatile("" ::: "memory");
}

__device__ __forceinline__ f32x16 mfma3(short8 ah, short8 al, short8 bh, short8 bl, f32x16 acc) {
  acc = __builtin_amdgcn_mfma_f32_32x32x16_bf16(ah, bh, acc, 0, 0, 0);
  acc = __builtin_amdgcn_mfma_f32_32x32x16_bf16(ah, bl, acc, 0, 0, 0);
  acc = __builtin_amdgcn_mfma_f32_32x32x16_bf16(al, bh, acc, 0, 0, 0);
  return acc;
}

// shared-A matmul: NP B-matrices against one A; XH = stage A ([x_f32 | h_slot])
template<int NP, int NBLK, bool XH>
__device__ __forceinline__ void mm_sharedA(const float* xrow, const ushort_t* aslot,
                                           const ushort_t* const (&bh)[NP],
                                           const ushort_t* const (&bl)[NP],
                                           int aoff, int boff, int kw,
                                           f32x16 (&acc)[NP]) {
#pragma unroll
  for (int j = 0; j < NBLK; ++j) {
    int kq = j * 128 + kw;
    short8 a_h, a_l;
    if (XH && j < 4) {
      xcvt(xrow + kq, a_h, a_l);
    } else {
      int kk = XH ? (kq - 512) : kq;
      a_h = ald16(aslot + aoff + kk);
      a_l = ald16(aslot + PLANE + aoff + kk);
    }
#pragma unroll
    for (int p = 0; p < NP; ++p) {
      short8 b_h = *(const short8*)(bh[p] + boff + kq);
      short8 b_l = *(const short8*)(bl[p] + boff + kq);
      acc[p] = mfma3(a_h, a_l, b_h, b_l, acc[p]);
    }
  }
}

// independent-A matmul: pair p uses A[p] and B[p] (stage D)
template<int NP, int NBLK>
__device__ __forceinline__ void mm_pairA(const ushort_t* const (&as)[NP],
                                         const ushort_t* const (&bh)[NP],
                                         const ushort_t* const (&bl)[NP],
                                         int aoff, int boff, int kw,
                                         f32x16 (&acc)[NP]) {
#pragma unroll
  for (int j = 0; j < NBLK; ++j) {
    int kq = j * 128 + kw;
#pragma unroll
    for (int p = 0; p < NP; ++p) {
      short8 a_h = ald16(as[p] + aoff + kq);
      short8 a_l = ald16(as[p] + PLANE + aoff + kq);
      short8 b_h = *(const short8*)(bh[p] + boff + kq);
      short8 b_l = *(const short8*)(bl[p] + boff + kq);
      acc[p] = mfma3(a_h, a_l, b_h, b_l, acc[p]);
    }
  }
}

template<int NP>
__device__ __forceinline__ void store_partials(float* pp, const f32x16 (&acc)[NP],
                                               int w, int lane) {
  int col = lane & 31, hi = lane >> 5;
#pragma unroll
  for (int p = 0; p < NP; ++p) {
#pragma unroll
    for (int r = 0; r < 16; ++r) {
      int row = (r & 3) + 8 * (r >> 2) + 4 * hi;   // verified 32x32 C/D layout
      pp[(w * NP + p) * 1056 + row * 33 + col] = acc[p][r];
    }
  }
}

template<int NP>
__device__ __forceinline__ void red2(const float* pp, int p, int row, int cp,
                                     float& c, float& h) {
  float cs = 0.f, hs = 0.f;
#pragma unroll
  for (int w = 0; w < 8; ++w) {
    cs += pp[(w * NP + p) * 1056 + row * 33 + cp];
    hs += pp[(w * NP + p) * 1056 + row * 33 + cp + 16];
  }
  c = cs; h = hs;
}

// ---------------- main persistent cooperative kernel -----------------------
extern "C" __global__ void __launch_bounds__(512, 1)
rnn_main(const float* __restrict__ x, float* __restrict__ out, char* __restrict__ ws) {
  __shared__ float pp[8 * 3 * 1056];      // 8-wave partials, up to 3 targets
  __shared__ float lst[6][32][16];        // WG-local f32 state tiles: h,s0,s1,s2,s3,s5
  ushort_t* stg = (ushort_t*)(ws + WS_ST);
  unsigned* flags = (unsigned*)(ws + WS_BAR);
  const ushort_t* w0h = (const ushort_t*)(ws + WS_W0T_HI);
  const ushort_t* w0l = (const ushort_t*)(ws + WS_W0T_LO);
  const ushort_t* wsh = (const ushort_t*)(ws + WS_WST_HI);
  const ushort_t* wsl = (const ushort_t*)(ws + WS_WST_LO);

  const int tid = threadIdx.x;
  const int wg = blockIdx.x;
  const int rt = wg >> 5, pt = wg & 31;   // 8 row-groups x 32 col-slots; xcd = wg%8 = pt%8
  const int g = rt;
  const int r0 = rt * 32;
  const int w = tid >> 6, lane = tid & 63;
  const int kw = w * 16 + (lane >> 5) * 8;            // this wave's K-offset within 128-block
  const int aoff = (r0 + (lane & 31)) * 512;          // A-frag row offset (elements)
  const int vcl = lane & 31;
  const int jc = pt * 16 + (vcl & 15) + (vcl >> 4) * 512;  // virtual col -> weight col j
  const int b512 = jc * 512, b1024 = jc * 1024;

  const int erow = tid >> 4, ecp = tid & 15;          // epilogue coords (512 elems)
  const int eo = (r0 + erow) * 512 + pt * 16 + ecp;   // global state element

  // init local h tile from global slot 0 (written by prep; plain read is fine here)
  lst[0][erow][ecp] = bf2f(stg[eo]) + bf2f(stg[PLANE + eo]);
  __syncthreads();

  unsigned gen = 1;
  float sumreg = 0.f;

  for (int t = 0; t < 400; ++t) {
    const float* xrow = x + (size_t)t * 131072 + (size_t)(r0 + (lane & 31)) * 512;

    // ---- stage A: s0 = h + sig(c)*(tanh(h0c) - h), A = [x | h], W0 (K=1024)
    {
      f32x16 acc[1] = {};
      const ushort_t* bh[1] = {w0h};
      const ushort_t* bl[1] = {w0l};
      mm_sharedA<1, 8, true>(xrow, stg + 0 * SLOT_ELEMS, bh, bl, aoff, b1024, kw, acc);
      __syncthreads();
      store_partials<1>(pp, acc, w, lane);
      __syncthreads();
      float c, h; red2<1>(pp, 0, erow, ecp, c, h);
      float sp = lst[0][erow][ecp];
      float s = sp + sigf(c) * (tanhf(h) - sp);
      lst[1][erow][ecp] = s;
      st_state(stg + 1 * SLOT_ELEMS, eo, s);
    }
    gbar(flags, g, pt, gen++);

    // ---- stage B: s1 = s0 + sig(c)*(tanh(h) - s0), Ws[0]
    {
      f32x16 acc[1] = {};
      const ushort_t* bh[1] = {wsh + 0 * 524288};
      const ushort_t* bl[1] = {wsl + 0 * 524288};
      mm_sharedA<1, 4, false>(nullptr, stg + 1 * SLOT_ELEMS, bh, bl, aoff, b512, kw, acc);
      __syncthreads();
      store_partials<1>(pp, acc, w, lane);
      __syncthreads();
      float c, h; red2<1>(pp, 0, erow, ecp, c, h);
      float sp = lst[1][erow][ecp];
      float s = sp + sigf(c) * (tanhf(h) - sp);
      lst[2][erow][ecp] = s;
      sumreg += s;
      st_state(stg + 2 * SLOT_ELEMS, eo, s);
    }
    gbar(flags, g, pt, gen++);

    // ---- stage C: s2(relu,Ws[1]) s3(relu,Ws[2]) s4(ident,Ws[3]), all from s1
    {
      f32x16 acc[3] = {};
      const ushort_t* bh[3] = {wsh + 1 * 524288, wsh + 2 * 524288, wsh + 3 * 524288};
      const ushort_t* bl[3] = {wsl + 1 * 524288, wsl + 2 * 524288, wsl + 3 * 524288};
      mm_sharedA<3, 4, false>(nullptr, stg + 2 * SLOT_ELEMS, bh, bl, aoff, b512, kw, acc);
      __syncthreads();
      store_partials<3>(pp, acc, w, lane);
      __syncthreads();
      float sp = lst[2][erow][ecp];
      float c, h;
      red2<3>(pp, 0, erow, ecp, c, h);                 // s2: relu
      float s2v = sp + sigf(c) * (fmaxf(h, 0.f) - sp);
      lst[3][erow][ecp] = s2v; sumreg += s2v;
      st_state(stg + 3 * SLOT_ELEMS, eo, s2v);
      red2<3>(pp, 1, erow, ecp, c, h);                 // s3: relu
      float s3v = sp + sigf(c) * (fmaxf(h, 0.f) - sp);
      lst[4][erow][ecp] = s3v; sumreg += s3v;
      st_state(stg + 4 * SLOT_ELEMS, eo, s3v);
      red2<3>(pp, 2, erow, ecp, c, h);                 // s4: identity, sum only
      sumreg += sp + sigf(c) * (h - sp);
    }
    gbar(flags, g, pt, gen++);

    // ---- stage D: s5 = f(s2,tanh,Ws[4]); s7 = f(s3,tanh,Ws[6])
    {
      f32x16 acc[2] = {};
      const ushort_t* as[2] = {stg + 3 * SLOT_ELEMS, stg + 4 * SLOT_ELEMS};
      const ushort_t* bh[2] = {wsh + 4 * 524288, wsh + 6 * 524288};
      const ushort_t* bl[2] = {wsl + 4 * 524288, wsl + 6 * 524288};
      mm_pairA<2, 4>(as, bh, bl, aoff, b512, kw, acc);
      __syncthreads();
      store_partials<2>(pp, acc, w, lane);
      __syncthreads();
      float c, h;
      red2<2>(pp, 0, erow, ecp, c, h);                 // s5
      float sp = lst[3][erow][ecp];
      float s5v = sp + sigf(c) * (tanhf(h) - sp);
      lst[5][erow][ecp] = s5v; sumreg += s5v;
      st_state(stg + 5 * SLOT_ELEMS, eo, s5v);
      red2<2>(pp, 1, erow, ecp, c, h);                 // s7: sum only
      float sp3 = lst[4][erow][ecp];
      sumreg += sp3 + sigf(c) * (tanhf(h) - sp3);
    }
    gbar(flags, g, pt, gen++);

    // ---- stage E: s6 = f(s5,sigmoid,Ws[5]); s8 = f(s5,relu,Ws[7]); mean; h
    {
      f32x16 acc[2] = {};
      const ushort_t* bh[2] = {wsh + 5 * 524288, wsh + 7 * 524288};
      const ushort_t* bl[2] = {wsl + 5 * 524288, wsl + 7 * 524288};
      mm_sharedA<2, 4, false>(nullptr, stg + 5 * SLOT_ELEMS, bh, bl, aoff, b512, kw, acc);
      __syncthreads();
      store_partials<2>(pp, acc, w, lane);
      __syncthreads();
      float c, h;
      float sp = lst[5][erow][ecp];
      red2<2>(pp, 0, erow, ecp, c, h);                 // s6: sigmoid
      sumreg += sp + sigf(c) * (sigf(h) - sp);
      red2<2>(pp, 1, erow, ecp, c, h);                 // s8: relu
      sumreg += sp + sigf(c) * (fmaxf(h, 0.f) - sp);
      float hn = sumreg * 0.125f;
      out[(size_t)t * 131072 + eo] = hn;
      if (t == 399) out[(size_t)400 * 131072 + eo] = hn;
      lst[0][erow][ecp] = hn;
      st_state(stg + 0 * SLOT_ELEMS, eo, hn);
      sumreg = 0.f;
    }
    gbar(flags, g, pt, gen++);
  }
}

// ---------------- host launch ----------------------------------------------
extern "C" void kernel_launch(void* const* d_in, const int* in_sizes, int n_in,
                              void* d_out, int out_size, void* d_ws, size_t ws_size,
                              hipStream_t stream) {
  const float* x  = (const float*)d_in[0];
  const float* h0 = (const float*)d_in[1];
  const float* W0 = (const float*)d_in[2];
  const float* Ws = (const float*)d_in[3];
  float* out = (float*)d_out;
  char* ws = (char*)d_ws;

  (void)in_sizes; (void)n_in; (void)out_size; (void)ws_size;

  (void)hipMemsetAsync(ws + WS_BAR, 0, 16384, stream);
  hipLaunchKernelGGL(prep_kernel, dim3(2048), dim3(256), 0, stream, W0, Ws, h0, ws);

  void* args[3] = {(void*)&x, (void*)&out, (void*)&ws};
  (void)hipLaunchCooperativeKernel((void*)rnn_main, dim3(256), dim3(512), args, 0, stream);
}